// Round 1
// baseline (462.749 us; speedup 1.0000x reference)
//
#include <hip/hip_runtime.h>
#include <hip/hip_bf16.h>

#define NB 2
#define SEQ 4096
#define DM 512
#define NH 8
#define DKH 64
#define MTOT (NB*SEQ)   // 8192

typedef __attribute__((ext_vector_type(4))) float f32x4;
typedef __attribute__((ext_vector_type(8))) short bf16x8;

__device__ inline unsigned short f2bf(float f) {
    union { float f; unsigned int u; } v; v.f = f;
    unsigned int r = v.u + 0x7FFFu + ((v.u >> 16) & 1u);
    return (unsigned short)(r >> 16);
}

// ---------------- cast fp32 -> bf16 for x, Wq, Wk, Wv, Wo ----------------
__global__ void cast_kernel(const float* __restrict__ x, const float* __restrict__ wq,
                            const float* __restrict__ wk, const float* __restrict__ wv,
                            const float* __restrict__ wo, unsigned short* __restrict__ dst) {
    const int NX = MTOT*DM;      // 4194304
    const int NW = DM*DM;        // 262144
    int i4 = blockIdx.x * blockDim.x + threadIdx.x;
    long e = (long)i4 * 4;
    if (e >= NX + 4L*NW) return;
    const float* src; long off;
    if (e < NX)           { src = x;  off = e; }
    else if (e < NX+NW)   { src = wq; off = e - NX; }
    else if (e < NX+2*NW) { src = wk; off = e - NX - NW; }
    else if (e < NX+3*NW) { src = wv; off = e - NX - 2*NW; }
    else                  { src = wo; off = e - NX - 3*NW; }
    float4 v = *reinterpret_cast<const float4*>(src + off);
    ushort4 o;
    o.x = f2bf(v.x); o.y = f2bf(v.y); o.z = f2bf(v.z); o.w = f2bf(v.w);
    *reinterpret_cast<ushort4*>(dst + e) = o;
}

// ---------------- B^T GEMM: C[M][N] = A[M][K] * B[N][K]^T ----------------
// MODE 0: A=Xbf[8192][512], B=Wqkv[1536][512]; scatter Q/K (per-head) and V (transposed per-head)
// MODE 1: A=Obf[8192][512], B=Wo[512][512]; C = fp32 out + b_o
template<int MODE>
__global__ __launch_bounds__(256, 2) void gemm_bt(
    const unsigned short* __restrict__ A,
    const unsigned short* __restrict__ B,
    const float* __restrict__ bias,      // MODE0: b_v, MODE1: b_o
    unsigned short* __restrict__ Qh, unsigned short* __restrict__ Kh,
    unsigned short* __restrict__ Vt,
    float* __restrict__ Cout)
{
    const int K = 512;
    __shared__ __align__(16) unsigned short As[128*64];
    __shared__ __align__(16) unsigned short Bs[128*64];
    int tid = threadIdx.x;
    int wid = tid >> 6, lane = tid & 63;
    int wr = wid >> 1, wc = wid & 1;
    int brow = blockIdx.x * 128;
    int bcol = blockIdx.y * 128;
    int l15 = lane & 15, l4 = lane >> 4;

    f32x4 acc[4][4] = {};

    for (int kt = 0; kt < K/64; ++kt) {
        __syncthreads();
        #pragma unroll
        for (int i = 0; i < 4; ++i) {
            int linear = tid + 256*i;
            int row = linear >> 3, col8 = linear & 7;
            int swz = (col8*16) ^ ((row & 7) << 4);
            bf16x8 av = *reinterpret_cast<const bf16x8*>(A + (long)(brow+row)*K + kt*64 + col8*8);
            *reinterpret_cast<bf16x8*>(reinterpret_cast<char*>(As) + row*128 + swz) = av;
            bf16x8 bv = *reinterpret_cast<const bf16x8*>(B + (long)(bcol+row)*K + kt*64 + col8*8);
            *reinterpret_cast<bf16x8*>(reinterpret_cast<char*>(Bs) + row*128 + swz) = bv;
        }
        __syncthreads();
        #pragma unroll
        for (int kk = 0; kk < 2; ++kk) {
            bf16x8 af[4], bfr[4];
            #pragma unroll
            for (int mi = 0; mi < 4; ++mi) {
                int row = wr*64 + mi*16 + l15;
                int colb = (kk*32 + l4*8) * 2;
                af[mi] = *reinterpret_cast<const bf16x8*>(
                    reinterpret_cast<const char*>(As) + row*128 + (colb ^ ((row&7)<<4)));
            }
            #pragma unroll
            for (int ni = 0; ni < 4; ++ni) {
                int row = wc*64 + ni*16 + l15;
                int colb = (kk*32 + l4*8) * 2;
                bfr[ni] = *reinterpret_cast<const bf16x8*>(
                    reinterpret_cast<const char*>(Bs) + row*128 + (colb ^ ((row&7)<<4)));
            }
            #pragma unroll
            for (int mi = 0; mi < 4; ++mi)
                #pragma unroll
                for (int ni = 0; ni < 4; ++ni)
                    acc[mi][ni] = __builtin_amdgcn_mfma_f32_16x16x32_bf16(af[mi], bfr[ni], acc[mi][ni], 0, 0, 0);
        }
    }

    #pragma unroll
    for (int mi = 0; mi < 4; ++mi) {
        #pragma unroll
        for (int ni = 0; ni < 4; ++ni) {
            #pragma unroll
            for (int r = 0; r < 4; ++r) {
                int row = brow + wr*64 + mi*16 + l4*4 + r;
                int col = bcol + wc*64 + ni*16 + l15;
                float v = acc[mi][ni][r];
                if (MODE == 0) {
                    int which = col >> 9;
                    int cw = col & 511;
                    int h = cw >> 6, d = cw & 63;
                    int b = row >> 12, s = row & 4095;
                    int bh = b*NH + h;
                    if (which == 0) {
                        Qh[((long)(bh*SEQ + s))*DKH + d] = f2bf(v * 0.125f);
                    } else if (which == 1) {
                        Kh[((long)(bh*SEQ + s))*DKH + d] = f2bf(v);
                    } else {
                        Vt[((long)(bh*DKH + d))*SEQ + s] = f2bf(v + bias[cw]);
                    }
                } else {
                    Cout[(long)row*DM + col] = v + bias[col];
                }
            }
        }
    }
}

// ---------------- causal flash attention ----------------
// grid: (64 qtiles, 16 bh); block: 256 = 4 waves, wave w owns q rows [q0+16w, q0+16w+16)
__global__ __launch_bounds__(256, 2) void attn_kernel(
    const unsigned short* __restrict__ Qh,
    const unsigned short* __restrict__ Kh,
    const unsigned short* __restrict__ Vt,
    unsigned short* __restrict__ Obf)
{
    __shared__ __align__(16) unsigned short P_lds[4][16*64];
    int tid = threadIdx.x;
    int wid = tid >> 6, lane = tid & 63;
    int l15 = lane & 15, l4 = lane >> 4;
    int qt = 63 - (int)blockIdx.x;   // long tiles first
    int bh = blockIdx.y;
    int q0 = qt * 64;
    int qrow0 = q0 + wid*16;

    const unsigned short* Qbase = Qh + (long)bh*SEQ*DKH;
    const unsigned short* Kbase = Kh + (long)bh*SEQ*DKH;
    const unsigned short* Vbase = Vt + (long)bh*DKH*SEQ;

    bf16x8 qf[2];
    #pragma unroll
    for (int c = 0; c < 2; ++c)
        qf[c] = *reinterpret_cast<const bf16x8*>(Qbase + (long)(qrow0 + l15)*DKH + c*32 + l4*8);

    float m[4], lsum[4];
    f32x4 o[4] = {};
    #pragma unroll
    for (int r = 0; r < 4; ++r) { m[r] = -1e30f; lsum[r] = 0.f; }

    char* pl = reinterpret_cast<char*>(P_lds[wid]);

    for (int kb = 0; kb <= qt; ++kb) {
        int key0 = kb*64;
        f32x4 s[4] = {};
        #pragma unroll
        for (int c = 0; c < 2; ++c) {
            #pragma unroll
            for (int kf = 0; kf < 4; ++kf) {
                bf16x8 kfrag = *reinterpret_cast<const bf16x8*>(
                    Kbase + (long)(key0 + kf*16 + l15)*DKH + c*32 + l4*8);
                s[kf] = __builtin_amdgcn_mfma_f32_16x16x32_bf16(qf[c], kfrag, s[kf], 0, 0, 0);
            }
        }
        if (kb == qt) {
            #pragma unroll
            for (int kf = 0; kf < 4; ++kf) {
                int key = key0 + kf*16 + l15;
                #pragma unroll
                for (int r = 0; r < 4; ++r) {
                    int q = qrow0 + l4*4 + r;
                    if (key > q) s[kf][r] = -1e30f;
                }
            }
        }
        float p[4][4];
        #pragma unroll
        for (int r = 0; r < 4; ++r) {
            float rowmax = fmaxf(fmaxf(s[0][r], s[1][r]), fmaxf(s[2][r], s[3][r]));
            #pragma unroll
            for (int d = 1; d < 16; d <<= 1)
                rowmax = fmaxf(rowmax, __shfl_xor(rowmax, d));
            float mn = fmaxf(m[r], rowmax);
            float alpha = __expf(m[r] - mn);
            m[r] = mn;
            float rs = 0.f;
            #pragma unroll
            for (int kf = 0; kf < 4; ++kf) {
                float pv = __expf(s[kf][r] - mn);
                p[kf][r] = pv;
                rs += pv;
            }
            #pragma unroll
            for (int d = 1; d < 16; d <<= 1)
                rs += __shfl_xor(rs, d);
            lsum[r] = lsum[r]*alpha + rs;
            #pragma unroll
            for (int df = 0; df < 4; ++df)
                o[df][r] *= alpha;
        }
        // P (C-layout) -> LDS bf16 (swizzled)
        #pragma unroll
        for (int kf = 0; kf < 4; ++kf) {
            #pragma unroll
            for (int r = 0; r < 4; ++r) {
                int row = l4*4 + r;
                int colb = (kf*16 + l15)*2;
                *reinterpret_cast<unsigned short*>(pl + row*128 + (colb ^ ((row&7)<<4))) = f2bf(p[kf][r]);
            }
        }
        // PV
        #pragma unroll
        for (int ks = 0; ks < 2; ++ks) {
            int colb = (ks*32 + l4*8)*2;
            bf16x8 pa = *reinterpret_cast<const bf16x8*>(pl + l15*128 + (colb ^ ((l15&7)<<4)));
            #pragma unroll
            for (int df = 0; df < 4; ++df) {
                bf16x8 vb = *reinterpret_cast<const bf16x8*>(
                    Vbase + (long)(df*16 + l15)*SEQ + key0 + ks*32 + l4*8);
                o[df] = __builtin_amdgcn_mfma_f32_16x16x32_bf16(pa, vb, o[df], 0, 0, 0);
            }
        }
    }
    int btok = (bh >> 3) * SEQ;
    int hcol = (bh & 7) * DKH;
    #pragma unroll
    for (int df = 0; df < 4; ++df) {
        #pragma unroll
        for (int r = 0; r < 4; ++r) {
            int tok = btok + qrow0 + l4*4 + r;
            int col = hcol + df*16 + l15;
            Obf[(long)tok*DM + col] = f2bf(o[df][r] / lsum[r]);
        }
    }
}

extern "C" void kernel_launch(void* const* d_in, const int* in_sizes, int n_in,
                              void* d_out, int out_size, void* d_ws, size_t ws_size,
                              hipStream_t stream) {
    const float* x  = (const float*)d_in[0];
    const float* wq = (const float*)d_in[1];
    const float* wk = (const float*)d_in[2];
    const float* wv = (const float*)d_in[3];
    const float* bv = (const float*)d_in[4];
    const float* wo = (const float*)d_in[5];
    const float* bo = (const float*)d_in[6];
    float* out = (float*)d_out;

    unsigned short* ws = (unsigned short*)d_ws;
    unsigned short* Xbf  = ws;                       // 8192*512
    unsigned short* Wqkv = Xbf  + 4194304;           // 1536*512
    unsigned short* Wob  = Wqkv + 786432;            // 512*512
    unsigned short* Qh   = Wob  + 262144;            // [16][4096][64]
    unsigned short* Kh   = Qh   + 4194304;           // [16][4096][64]
    unsigned short* Vt   = Kh   + 4194304;           // [16][64][4096]
    unsigned short* Obf  = Vt   + 4194304;           // [8192][512]

    cast_kernel<<<5120, 256, 0, stream>>>(x, wq, wk, wv, wo, Xbf);

    dim3 g1(64, 12);
    gemm_bt<0><<<g1, 256, 0, stream>>>(Xbf, Wqkv, bv, Qh, Kh, Vt, nullptr);

    dim3 g2(64, 16);
    attn_kernel<<<g2, 256, 0, stream>>>(Qh, Kh, Vt, Obf);

    dim3 g3(64, 4);
    gemm_bt<1><<<g3, 256, 0, stream>>>(Obf, Wob, bo, nullptr, nullptr, nullptr, out);
}

// Round 2
// 184.222 us; speedup vs baseline: 2.5119x; 2.5119x over previous
//
#include <hip/hip_runtime.h>
#include <hip/hip_bf16.h>

#define NB 2
#define SEQ 4096
#define DM 512
#define NH 8
#define DKH 64
#define MTOT (NB*SEQ)   // 8192

typedef __attribute__((ext_vector_type(4))) float f32x4;
typedef __attribute__((ext_vector_type(8))) short bf16x8;

__device__ inline unsigned short f2bf(float f) {
    union { float f; unsigned int u; } v; v.f = f;
    unsigned int r = v.u + 0x7FFFu + ((v.u >> 16) & 1u);
    return (unsigned short)(r >> 16);
}

// Q prescale: 1/sqrt(d_k) * log2(e) so softmax runs in exp2 domain
#define QSCALE 0.18033688011112042f

// ---------------- cast fp32 -> bf16 for x, Wq, Wk, Wv, Wo ----------------
__global__ void cast_kernel(const float* __restrict__ x, const float* __restrict__ wq,
                            const float* __restrict__ wk, const float* __restrict__ wv,
                            const float* __restrict__ wo, unsigned short* __restrict__ dst) {
    const int NX = MTOT*DM;      // 4194304
    const int NW = DM*DM;        // 262144
    int i4 = blockIdx.x * blockDim.x + threadIdx.x;
    long e = (long)i4 * 4;
    if (e >= NX + 4L*NW) return;
    const float* src; long off;
    if (e < NX)           { src = x;  off = e; }
    else if (e < NX+NW)   { src = wq; off = e - NX; }
    else if (e < NX+2*NW) { src = wk; off = e - NX - NW; }
    else if (e < NX+3*NW) { src = wv; off = e - NX - 2*NW; }
    else                  { src = wo; off = e - NX - 3*NW; }
    float4 v = *reinterpret_cast<const float4*>(src + off);
    ushort4 o;
    o.x = f2bf(v.x); o.y = f2bf(v.y); o.z = f2bf(v.z); o.w = f2bf(v.w);
    *reinterpret_cast<ushort4*>(dst + e) = o;
}

// ---------------- B^T GEMM: C[M][N] = A[M][K] * B[N][K]^T ----------------
template<int MODE>
__global__ __launch_bounds__(256, 2) void gemm_bt(
    const unsigned short* __restrict__ A,
    const unsigned short* __restrict__ B,
    const float* __restrict__ bias,      // MODE0: b_v, MODE1: b_o
    unsigned short* __restrict__ Qh, unsigned short* __restrict__ Kh,
    unsigned short* __restrict__ Vt,
    float* __restrict__ Cout)
{
    const int K = 512;
    __shared__ __align__(16) unsigned short As[128*64];
    __shared__ __align__(16) unsigned short Bs[128*64];
    int tid = threadIdx.x;
    int wid = tid >> 6, lane = tid & 63;
    int wr = wid >> 1, wc = wid & 1;
    int brow = blockIdx.x * 128;
    int bcol = blockIdx.y * 128;
    int l15 = lane & 15, l4 = lane >> 4;

    f32x4 acc[4][4] = {};

    for (int kt = 0; kt < K/64; ++kt) {
        __syncthreads();
        #pragma unroll
        for (int i = 0; i < 4; ++i) {
            int linear = tid + 256*i;
            int row = linear >> 3, col8 = linear & 7;
            int swz = (col8*16) ^ ((row & 7) << 4);
            bf16x8 av = *reinterpret_cast<const bf16x8*>(A + (long)(brow+row)*K + kt*64 + col8*8);
            *reinterpret_cast<bf16x8*>(reinterpret_cast<char*>(As) + row*128 + swz) = av;
            bf16x8 bv = *reinterpret_cast<const bf16x8*>(B + (long)(bcol+row)*K + kt*64 + col8*8);
            *reinterpret_cast<bf16x8*>(reinterpret_cast<char*>(Bs) + row*128 + swz) = bv;
        }
        __syncthreads();
        #pragma unroll
        for (int kk = 0; kk < 2; ++kk) {
            bf16x8 af[4], bfr[4];
            #pragma unroll
            for (int mi = 0; mi < 4; ++mi) {
                int row = wr*64 + mi*16 + l15;
                int colb = (kk*32 + l4*8) * 2;
                af[mi] = *reinterpret_cast<const bf16x8*>(
                    reinterpret_cast<const char*>(As) + row*128 + (colb ^ ((row&7)<<4)));
            }
            #pragma unroll
            for (int ni = 0; ni < 4; ++ni) {
                int row = wc*64 + ni*16 + l15;
                int colb = (kk*32 + l4*8) * 2;
                bfr[ni] = *reinterpret_cast<const bf16x8*>(
                    reinterpret_cast<const char*>(Bs) + row*128 + (colb ^ ((row&7)<<4)));
            }
            #pragma unroll
            for (int mi = 0; mi < 4; ++mi)
                #pragma unroll
                for (int ni = 0; ni < 4; ++ni)
                    acc[mi][ni] = __builtin_amdgcn_mfma_f32_16x16x32_bf16(af[mi], bfr[ni], acc[mi][ni], 0, 0, 0);
        }
    }

    #pragma unroll
    for (int mi = 0; mi < 4; ++mi) {
        #pragma unroll
        for (int ni = 0; ni < 4; ++ni) {
            #pragma unroll
            for (int r = 0; r < 4; ++r) {
                int row = brow + wr*64 + mi*16 + l4*4 + r;
                int col = bcol + wc*64 + ni*16 + l15;
                float v = acc[mi][ni][r];
                if (MODE == 0) {
                    int which = col >> 9;
                    int cw = col & 511;
                    int h = cw >> 6, d = cw & 63;
                    int b = row >> 12, s = row & 4095;
                    int bh = b*NH + h;
                    if (which == 0) {
                        Qh[((long)(bh*SEQ + s))*DKH + d] = f2bf(v * QSCALE);
                    } else if (which == 1) {
                        Kh[((long)(bh*SEQ + s))*DKH + d] = f2bf(v);
                    } else {
                        Vt[((long)(bh*DKH + d))*SEQ + s] = f2bf(v + bias[cw]);
                    }
                } else {
                    Cout[(long)row*DM + col] = v + bias[col];
                }
            }
        }
    }
}

// ---------------- causal flash attention (LDS-staged, paired tiles) ----------------
// grid: (32 tile-pairs, 16 bh); block 256 = 4 waves; each block does q-tiles
// 63-bx and bx sequentially (65 key-block iterations total, uniform).
__global__ __launch_bounds__(256, 2) void attn_kernel(
    const unsigned short* __restrict__ Qh,
    const unsigned short* __restrict__ Kh,
    const unsigned short* __restrict__ Vt,
    unsigned short* __restrict__ Obf)
{
    __shared__ __align__(16) unsigned short Klds[2][64*64];
    __shared__ __align__(16) unsigned short Vlds[2][64*64];
    __shared__ __align__(16) unsigned short P_lds[4][16*64];
    const int tid = threadIdx.x;
    const int wid = tid >> 6, lane = tid & 63;
    const int l15 = lane & 15, l4 = lane >> 4;
    const int bh = blockIdx.y;

    const unsigned short* Qbase = Qh + (long)bh*SEQ*DKH;
    const unsigned short* Kbase = Kh + (long)bh*SEQ*DKH;
    const unsigned short* Vbase = Vt + (long)bh*DKH*SEQ;
    char* pl = reinterpret_cast<char*>(P_lds[wid]);
    const int srow0 = wid*16;   // staging rows owned by this wave

    // stage K/V tile for key block key0 into buffer b (linear LDS dest,
    // inverse-swizzled global source; reads use XOR swizzle)
    auto STAGE = [&](int b, int key0) {
        #pragma unroll
        for (int ii = 0; ii < 2; ++ii) {
            const int k0 = srow0 + ii*8;
            const int row = k0 + (lane >> 3);
            const int ck = (lane & 7) ^ (row & 7);
            const unsigned short* ksrc = Kbase + (long)(key0 + row)*DKH + ck*8;
            __builtin_amdgcn_global_load_lds(
                (const __attribute__((address_space(1))) unsigned int*)ksrc,
                (__attribute__((address_space(3))) unsigned int*)&Klds[b][k0*64], 16, 0, 0);
            const unsigned short* vsrc = Vbase + (long)row*SEQ + key0 + ck*8;
            __builtin_amdgcn_global_load_lds(
                (const __attribute__((address_space(1))) unsigned int*)vsrc,
                (__attribute__((address_space(3))) unsigned int*)&Vlds[b][k0*64], 16, 0, 0);
        }
    };

    #pragma unroll 1
    for (int half = 0; half < 2; ++half) {
        const int qt = half ? (int)blockIdx.x : 63 - (int)blockIdx.x;
        const int qrow0 = qt*64 + wid*16;

        bf16x8 qf[2];
        #pragma unroll
        for (int c = 0; c < 2; ++c)
            qf[c] = *reinterpret_cast<const bf16x8*>(Qbase + (long)(qrow0 + l15)*DKH + c*32 + l4*8);

        float m[4], lsum[4];
        f32x4 o[4] = {};
        #pragma unroll
        for (int r = 0; r < 4; ++r) { m[r] = -1e30f; lsum[r] = 0.f; }

        const int nt = qt + 1;
        __syncthreads();
        STAGE(0, 0);
        __syncthreads();          // implicit vmcnt(0): buf0 ready
        int cur = 0;

        for (int kb = 0; kb < nt; ++kb) {
            if (kb + 1 < nt) STAGE(cur ^ 1, (kb + 1) << 6);

            const char* kl = reinterpret_cast<const char*>(Klds[cur]);
            const char* vl = reinterpret_cast<const char*>(Vlds[cur]);
            const int key0 = kb << 6;

            f32x4 s[4] = {};
            #pragma unroll
            for (int c = 0; c < 2; ++c) {
                #pragma unroll
                for (int kf = 0; kf < 4; ++kf) {
                    const int row = kf*16 + l15;
                    bf16x8 kfrag = *reinterpret_cast<const bf16x8*>(
                        kl + row*128 + ((c*64 + l4*16) ^ ((row & 7) << 4)));
                    s[kf] = __builtin_amdgcn_mfma_f32_16x16x32_bf16(qf[c], kfrag, s[kf], 0, 0, 0);
                }
            }
            if (kb == qt) {
                #pragma unroll
                for (int kf = 0; kf < 4; ++kf) {
                    const int key = key0 + kf*16 + l15;
                    #pragma unroll
                    for (int r = 0; r < 4; ++r) {
                        const int q = qrow0 + l4*4 + r;
                        if (key > q) s[kf][r] = -1e30f;
                    }
                }
            }

            // row maxes (uniform across each 16-lane group)
            float rowmax[4];
            #pragma unroll
            for (int r = 0; r < 4; ++r) {
                float mx = fmaxf(fmaxf(s[0][r], s[1][r]), fmaxf(s[2][r], s[3][r]));
                #pragma unroll
                for (int d = 1; d < 16; d <<= 1)
                    mx = fmaxf(mx, __shfl_xor(mx, d));
                rowmax[r] = mx;
            }
            bool grow = (rowmax[0] > m[0]) | (rowmax[1] > m[1]) |
                        (rowmax[2] > m[2]) | (rowmax[3] > m[3]);
            float p[4][4];
            if (__any(grow)) {
                #pragma unroll
                for (int r = 0; r < 4; ++r) {
                    const float mn = fmaxf(m[r], rowmax[r]);
                    const float alpha = __builtin_amdgcn_exp2f(m[r] - mn);
                    m[r] = mn;
                    float rs = 0.f;
                    #pragma unroll
                    for (int kf = 0; kf < 4; ++kf) {
                        const float pv = __builtin_amdgcn_exp2f(s[kf][r] - mn);
                        p[kf][r] = pv;
                        rs += pv;
                    }
                    lsum[r] = lsum[r]*alpha + rs;   // per-lane partial
                    #pragma unroll
                    for (int df = 0; df < 4; ++df)
                        o[df][r] *= alpha;
                }
            } else {
                #pragma unroll
                for (int r = 0; r < 4; ++r) {
                    float rs = 0.f;
                    #pragma unroll
                    for (int kf = 0; kf < 4; ++kf) {
                        const float pv = __builtin_amdgcn_exp2f(s[kf][r] - m[r]);
                        p[kf][r] = pv;
                        rs += pv;
                    }
                    lsum[r] += rs;
                }
            }

            // P (C-layout) -> per-wave LDS bf16 (swizzled)
            #pragma unroll
            for (int kf = 0; kf < 4; ++kf) {
                #pragma unroll
                for (int r = 0; r < 4; ++r) {
                    const int row = l4*4 + r;
                    const int colb = (kf*16 + l15)*2;
                    *reinterpret_cast<unsigned short*>(pl + row*128 + (colb ^ ((row&7)<<4))) = f2bf(p[kf][r]);
                }
            }
            // PV
            #pragma unroll
            for (int ks = 0; ks < 2; ++ks) {
                bf16x8 pa = *reinterpret_cast<const bf16x8*>(
                    pl + l15*128 + ((ks*64 + l4*16) ^ ((l15&7)<<4)));
                #pragma unroll
                for (int df = 0; df < 4; ++df) {
                    const int vrow = df*16 + l15;
                    bf16x8 vb = *reinterpret_cast<const bf16x8*>(
                        vl + vrow*128 + ((ks*64 + l4*16) ^ ((vrow&7)<<4)));
                    o[df] = __builtin_amdgcn_mfma_f32_16x16x32_bf16(pa, vb, o[df], 0, 0, 0);
                }
            }
            __syncthreads();
            cur ^= 1;
        }

        // epilogue: reduce per-lane lsum partials across the 16-lane group, write O
        #pragma unroll
        for (int r = 0; r < 4; ++r) {
            float t = lsum[r];
            #pragma unroll
            for (int d = 1; d < 16; d <<= 1)
                t += __shfl_xor(t, d);
            lsum[r] = 1.0f / t;
        }
        const int btok = (bh >> 3) * SEQ;
        const int hcol = (bh & 7) * DKH;
        #pragma unroll
        for (int df = 0; df < 4; ++df) {
            #pragma unroll
            for (int r = 0; r < 4; ++r) {
                const int tok = btok + qrow0 + l4*4 + r;
                const int col = hcol + df*16 + l15;
                Obf[(long)tok*DM + col] = f2bf(o[df][r] * lsum[r]);
            }
        }
    }
}

extern "C" void kernel_launch(void* const* d_in, const int* in_sizes, int n_in,
                              void* d_out, int out_size, void* d_ws, size_t ws_size,
                              hipStream_t stream) {
    const float* x  = (const float*)d_in[0];
    const float* wq = (const float*)d_in[1];
    const float* wk = (const float*)d_in[2];
    const float* wv = (const float*)d_in[3];
    const float* bv = (const float*)d_in[4];
    const float* wo = (const float*)d_in[5];
    const float* bo = (const float*)d_in[6];
    float* out = (float*)d_out;

    unsigned short* ws = (unsigned short*)d_ws;
    unsigned short* Xbf  = ws;                       // 8192*512
    unsigned short* Wqkv = Xbf  + 4194304;           // 1536*512
    unsigned short* Wob  = Wqkv + 786432;            // 512*512
    unsigned short* Qh   = Wob  + 262144;            // [16][4096][64]
    unsigned short* Kh   = Qh   + 4194304;           // [16][4096][64]
    unsigned short* Vt   = Kh   + 4194304;           // [16][64][4096]
    unsigned short* Obf  = Vt   + 4194304;           // [8192][512]

    cast_kernel<<<5120, 256, 0, stream>>>(x, wq, wk, wv, wo, Xbf);

    dim3 g1(64, 12);
    gemm_bt<0><<<g1, 256, 0, stream>>>(Xbf, Wqkv, bv, Qh, Kh, Vt, nullptr);

    dim3 g2(32, 16);
    attn_kernel<<<g2, 256, 0, stream>>>(Qh, Kh, Vt, Obf);

    dim3 g3(64, 4);
    gemm_bt<1><<<g3, 256, 0, stream>>>(Obf, Wob, bo, nullptr, nullptr, nullptr, out);
}

// Round 4
// 133.490 us; speedup vs baseline: 3.4665x; 1.3800x over previous
//
#include <hip/hip_runtime.h>
#include <hip/hip_bf16.h>

#define NB 2
#define SEQ 4096
#define DM 512
#define NH 8
#define DKH 64
#define MTOT (NB*SEQ)   // 8192

typedef __attribute__((ext_vector_type(4))) float f32x4;
typedef __attribute__((ext_vector_type(16))) float f32x16;
typedef __attribute__((ext_vector_type(8))) short bf16x8;
typedef __attribute__((ext_vector_type(2))) unsigned uint2v;

__device__ inline unsigned short f2bf(float f) {
    union { float f; unsigned int u; } v; v.f = f;
    unsigned int r = v.u + 0x7FFFu + ((v.u >> 16) & 1u);
    return (unsigned short)(r >> 16);
}

// Q prescale: 1/sqrt(d_k) * log2(e) so softmax runs in exp2 domain
#define QSCALE 0.18033688011112042f

// ---------------- cast fp32 -> bf16 for x, Wq, Wk, Wv, Wo ----------------
__global__ void cast_kernel(const float* __restrict__ x, const float* __restrict__ wq,
                            const float* __restrict__ wk, const float* __restrict__ wv,
                            const float* __restrict__ wo, unsigned short* __restrict__ dst) {
    const int NX = MTOT*DM;      // 4194304
    const int NW = DM*DM;        // 262144
    int i4 = blockIdx.x * blockDim.x + threadIdx.x;
    long e = (long)i4 * 4;
    if (e >= NX + 4L*NW) return;
    const float* src; long off;
    if (e < NX)           { src = x;  off = e; }
    else if (e < NX+NW)   { src = wq; off = e - NX; }
    else if (e < NX+2*NW) { src = wk; off = e - NX - NW; }
    else if (e < NX+3*NW) { src = wv; off = e - NX - 2*NW; }
    else                  { src = wo; off = e - NX - 3*NW; }
    float4 v = *reinterpret_cast<const float4*>(src + off);
    ushort4 o;
    o.x = f2bf(v.x); o.y = f2bf(v.y); o.z = f2bf(v.z); o.w = f2bf(v.w);
    *reinterpret_cast<ushort4*>(dst + e) = o;
}

// ---------------- B^T GEMM: C[M][N] = A[M][K] * B[N][K]^T ----------------
template<int MODE>
__global__ __launch_bounds__(256, 2) void gemm_bt(
    const unsigned short* __restrict__ A,
    const unsigned short* __restrict__ B,
    const float* __restrict__ bias,      // MODE0: b_v, MODE1: b_o
    unsigned short* __restrict__ Qh, unsigned short* __restrict__ Kh,
    unsigned short* __restrict__ Vt,
    float* __restrict__ Cout)
{
    const int K = 512;
    __shared__ __align__(16) unsigned short As[128*64];
    __shared__ __align__(16) unsigned short Bs[128*64];
    int tid = threadIdx.x;
    int wid = tid >> 6, lane = tid & 63;
    int wr = wid >> 1, wc = wid & 1;
    int brow = blockIdx.x * 128;
    int bcol = blockIdx.y * 128;
    int l15 = lane & 15, l4 = lane >> 4;

    f32x4 acc[4][4] = {};

    for (int kt = 0; kt < K/64; ++kt) {
        __syncthreads();
        // global -> LDS direct (linear dest, inverse-swizzled per-lane source)
        #pragma unroll
        for (int i = 0; i < 4; ++i) {
            int rbase = i*32 + wid*8;
            int row = rbase + (lane >> 3);
            int csrc = (lane & 7) ^ (row & 7);
            const unsigned short* asrc = A + (long)(brow+row)*K + kt*64 + csrc*8;
            __builtin_amdgcn_global_load_lds(
                (const __attribute__((address_space(1))) unsigned int*)asrc,
                (__attribute__((address_space(3))) unsigned int*)&As[rbase*64], 16, 0, 0);
            const unsigned short* bsrc = B + (long)(bcol+row)*K + kt*64 + csrc*8;
            __builtin_amdgcn_global_load_lds(
                (const __attribute__((address_space(1))) unsigned int*)bsrc,
                (__attribute__((address_space(3))) unsigned int*)&Bs[rbase*64], 16, 0, 0);
        }
        __syncthreads();
        #pragma unroll
        for (int kk = 0; kk < 2; ++kk) {
            bf16x8 af[4], bfr[4];
            #pragma unroll
            for (int mi = 0; mi < 4; ++mi) {
                int row = wr*64 + mi*16 + l15;
                int colb = (kk*32 + l4*8) * 2;
                af[mi] = *reinterpret_cast<const bf16x8*>(
                    reinterpret_cast<const char*>(As) + row*128 + (colb ^ ((row&7)<<4)));
            }
            #pragma unroll
            for (int ni = 0; ni < 4; ++ni) {
                int row = wc*64 + ni*16 + l15;
                int colb = (kk*32 + l4*8) * 2;
                bfr[ni] = *reinterpret_cast<const bf16x8*>(
                    reinterpret_cast<const char*>(Bs) + row*128 + (colb ^ ((row&7)<<4)));
            }
            #pragma unroll
            for (int mi = 0; mi < 4; ++mi)
                #pragma unroll
                for (int ni = 0; ni < 4; ++ni)
                    acc[mi][ni] = __builtin_amdgcn_mfma_f32_16x16x32_bf16(af[mi], bfr[ni], acc[mi][ni], 0, 0, 0);
        }
    }

    #pragma unroll
    for (int mi = 0; mi < 4; ++mi) {
        #pragma unroll
        for (int ni = 0; ni < 4; ++ni) {
            #pragma unroll
            for (int r = 0; r < 4; ++r) {
                int row = brow + wr*64 + mi*16 + l4*4 + r;
                int col = bcol + wc*64 + ni*16 + l15;
                float v = acc[mi][ni][r];
                if (MODE == 0) {
                    int which = col >> 9;
                    int cw = col & 511;
                    int h = cw >> 6, d = cw & 63;
                    int b = row >> 12, s = row & 4095;
                    int bh = b*NH + h;
                    if (which == 0) {
                        Qh[((long)(bh*SEQ + s))*DKH + d] = f2bf(v * QSCALE);
                    } else if (which == 1) {
                        Kh[((long)(bh*SEQ + s))*DKH + d] = f2bf(v);
                    } else {
                        Vt[((long)(bh*DKH + d))*SEQ + s] = f2bf(v + bias[cw]);
                    }
                } else {
                    Cout[(long)row*DM + col] = v + bias[col];
                }
            }
        }
    }
}

// ---------------- causal flash attention: 32x32 swapped-operand structure ----
// grid (16 bh, 32 ty); block 256 = 4 waves; wave owns 32 q-rows (tile = 128).
// S^T = mfma(K,Q): lane holds 32 scores of ONE q-row -> in-lane softmax.
// O^T = mfma(Vt,P^T): O accumulator has q = lane&31 -> per-lane alpha/lsum.
__global__ __launch_bounds__(256, 2) void attn_kernel(
    const unsigned short* __restrict__ Qh,
    const unsigned short* __restrict__ Kh,
    const unsigned short* __restrict__ Vt,
    unsigned short* __restrict__ Obf)
{
    __shared__ __align__(16) unsigned short Klds[2][64*64];
    __shared__ __align__(16) unsigned short Vlds[2][64*64];
    const int tid = threadIdx.x;
    const int wid = tid >> 6, lane = tid & 63;
    const int l31 = lane & 31;
    const int hi  = lane >> 5;
    const int bh  = blockIdx.x;
    const int ty  = blockIdx.y;
    const int tile = ty < 16 ? 31 - ty : ty - 16;   // dispatch-order pairing

    const unsigned short* Qbase = Qh + (long)bh*SEQ*DKH;
    const unsigned short* Kbase = Kh + (long)bh*SEQ*DKH;
    const unsigned short* Vbase = Vt + (long)bh*DKH*SEQ;

    const int q0w = tile*128 + wid*32;
    const int q   = q0w + l31;
    const int nt  = 2*tile + 2;
    const int swz = (l31 & 7) << 4;

    // Q as B-operand frags: qf[kk][e] = Q[q][kk*16 + hi*8 + e]
    bf16x8 qf[4];
    #pragma unroll
    for (int kk = 0; kk < 4; ++kk)
        qf[kk] = *reinterpret_cast<const bf16x8*>(Qbase + (long)q*DKH + kk*16 + hi*8);

    auto STAGE = [&](int b, int key0) {
        #pragma unroll
        for (int ii = 0; ii < 2; ++ii) {
            const int rbase = wid*16 + ii*8;
            const int row = rbase + (lane >> 3);
            const int ck = (lane & 7) ^ (row & 7);
            const unsigned short* ksrc = Kbase + (long)(key0 + row)*DKH + ck*8;
            __builtin_amdgcn_global_load_lds(
                (const __attribute__((address_space(1))) unsigned int*)ksrc,
                (__attribute__((address_space(3))) unsigned int*)&Klds[b][rbase*64], 16, 0, 0);
            const unsigned short* vsrc = Vbase + (long)row*SEQ + key0 + ck*8;
            __builtin_amdgcn_global_load_lds(
                (const __attribute__((address_space(1))) unsigned int*)vsrc,
                (__attribute__((address_space(3))) unsigned int*)&Vlds[b][rbase*64], 16, 0, 0);
        }
    };

    float m = -1e30f, lsum = 0.f;
    f32x16 od0 = {}, od1 = {};

    STAGE(0, 0);
    __syncthreads();
    int cur = 0;

    for (int kb = 0; kb < nt; ++kb) {
        if (kb + 1 < nt) STAGE(cur ^ 1, (kb + 1) << 6);
        const char* kl = reinterpret_cast<const char*>(Klds[cur]);
        const char* vl = reinterpret_cast<const char*>(Vlds[cur]);
        const int key0 = kb << 6;

        // QK^T (swapped): s0 = keys key0..+31, s1 = keys key0+32..+63
        f32x16 s0 = {}, s1 = {};
        __builtin_amdgcn_s_setprio(1);
        #pragma unroll
        for (int kk = 0; kk < 4; ++kk) {
            bf16x8 kf0 = *reinterpret_cast<const bf16x8*>(kl + l31*128      + ((kk*32 + hi*16) ^ swz));
            s0 = __builtin_amdgcn_mfma_f32_32x32x16_bf16(kf0, qf[kk], s0, 0, 0, 0);
            bf16x8 kf1 = *reinterpret_cast<const bf16x8*>(kl + (32+l31)*128 + ((kk*32 + hi*16) ^ swz));
            s1 = __builtin_amdgcn_mfma_f32_32x32x16_bf16(kf1, qf[kk], s1, 0, 0, 0);
        }
        __builtin_amdgcn_s_setprio(0);

        // causal mask: key index of reg r is key0 + (r&3)+8*(r>>2)+4*hi (+32 for s1)
        if (key0 + 63 > q0w) {
            #pragma unroll
            for (int r = 0; r < 16; ++r) {
                const int ko = (r&3) + 8*(r>>2) + 4*hi;
                if (key0 + ko > q)      s0[r] = -1e30f;
                if (key0 + 32 + ko > q) s1[r] = -1e30f;
            }
        }

        // row max: in-lane tree + partner exchange (builtin: proper 2-result SSA)
        float pmax = s0[0];
        #pragma unroll
        for (int r = 1; r < 16; ++r) pmax = fmaxf(pmax, s0[r]);
        #pragma unroll
        for (int r = 0; r < 16; ++r) pmax = fmaxf(pmax, s1[r]);
        {
            uint2v pr = __builtin_amdgcn_permlane32_swap(__float_as_uint(pmax), __float_as_uint(pmax), false, false);
            pmax = fmaxf(__uint_as_float(pr[0]), __uint_as_float(pr[1]));
        }

        // defer-max (T13): rescale only when max grows past threshold
        if (__any(pmax > m + 6.0f)) {
            const float mn = fmaxf(m, pmax);
            const float alpha = __builtin_amdgcn_exp2f(m - mn);
            m = mn;
            lsum *= alpha;
            #pragma unroll
            for (int r = 0; r < 16; ++r) { od0[r] *= alpha; od1[r] *= alpha; }
        }

        // P = exp2(S - m), in place; accumulate per-lane lsum partial
        #pragma unroll
        for (int r = 0; r < 16; ++r) {
            s0[r] = __builtin_amdgcn_exp2f(s0[r] - m);
            s1[r] = __builtin_amdgcn_exp2f(s1[r] - m);
        }
        float rs = 0.f;
        #pragma unroll
        for (int r = 0; r < 16; ++r) rs += s0[r] + s1[r];
        lsum += rs;

        // P -> bf16 B-frags in-register (cvt_pk + permlane32_swap), then PV
        __builtin_amdgcn_s_setprio(1);
#define PV_STEP(SV, KS, B0) do {                                                   \
        unsigned c0, c1, c2, c3;                                                   \
        float t0 = SV[B0+0], t1 = SV[B0+1], t2 = SV[B0+2], t3 = SV[B0+3];          \
        float t4 = SV[B0+4], t5 = SV[B0+5], t6 = SV[B0+6], t7 = SV[B0+7];          \
        asm("v_cvt_pk_bf16_f32 %0, %1, %2" : "=v"(c0) : "v"(t0), "v"(t1));         \
        asm("v_cvt_pk_bf16_f32 %0, %1, %2" : "=v"(c1) : "v"(t2), "v"(t3));         \
        asm("v_cvt_pk_bf16_f32 %0, %1, %2" : "=v"(c2) : "v"(t4), "v"(t5));         \
        asm("v_cvt_pk_bf16_f32 %0, %1, %2" : "=v"(c3) : "v"(t6), "v"(t7));         \
        uint2v sw0 = __builtin_amdgcn_permlane32_swap(c0, c2, false, false);       \
        uint2v sw1 = __builtin_amdgcn_permlane32_swap(c1, c3, false, false);       \
        union { unsigned u[4]; bf16x8 v; } pu;                                     \
        pu.u[0] = sw0[0]; pu.u[1] = sw1[0]; pu.u[2] = sw0[1]; pu.u[3] = sw1[1];    \
        bf16x8 vf0 = *reinterpret_cast<const bf16x8*>(vl + l31*128      + ((KS*32 + hi*16) ^ swz)); \
        od0 = __builtin_amdgcn_mfma_f32_32x32x16_bf16(vf0, pu.v, od0, 0, 0, 0);    \
        bf16x8 vf1 = *reinterpret_cast<const bf16x8*>(vl + (32+l31)*128 + ((KS*32 + hi*16) ^ swz)); \
        od1 = __builtin_amdgcn_mfma_f32_32x32x16_bf16(vf1, pu.v, od1, 0, 0, 0);    \
    } while (0)
        PV_STEP(s0, 0, 0);
        PV_STEP(s0, 1, 8);
        PV_STEP(s1, 2, 0);
        PV_STEP(s1, 3, 8);
#undef PV_STEP
        __builtin_amdgcn_s_setprio(0);

        __syncthreads();
        cur ^= 1;
    }

    // combine partner lsum, normalize, write O
    {
        uint2v pr = __builtin_amdgcn_permlane32_swap(__float_as_uint(lsum), __float_as_uint(lsum), false, false);
        lsum = __uint_as_float(pr[0]) + __uint_as_float(pr[1]);
    }
    const float rls = 1.0f / lsum;
    const long obase = (long)((bh >> 3)*SEQ + q)*DM + (bh & 7)*DKH;
    #pragma unroll
    for (int rr = 0; rr < 4; ++rr) {
        ushort4 w0, w1;
        w0.x = f2bf(od0[rr*4+0]*rls); w0.y = f2bf(od0[rr*4+1]*rls);
        w0.z = f2bf(od0[rr*4+2]*rls); w0.w = f2bf(od0[rr*4+3]*rls);
        *reinterpret_cast<ushort4*>(Obf + obase + rr*8 + hi*4) = w0;
        w1.x = f2bf(od1[rr*4+0]*rls); w1.y = f2bf(od1[rr*4+1]*rls);
        w1.z = f2bf(od1[rr*4+2]*rls); w1.w = f2bf(od1[rr*4+3]*rls);
        *reinterpret_cast<ushort4*>(Obf + obase + 32 + rr*8 + hi*4) = w1;
    }
}

extern "C" void kernel_launch(void* const* d_in, const int* in_sizes, int n_in,
                              void* d_out, int out_size, void* d_ws, size_t ws_size,
                              hipStream_t stream) {
    const float* x  = (const float*)d_in[0];
    const float* wq = (const float*)d_in[1];
    const float* wk = (const float*)d_in[2];
    const float* wv = (const float*)d_in[3];
    const float* bv = (const float*)d_in[4];
    const float* wo = (const float*)d_in[5];
    const float* bo = (const float*)d_in[6];
    float* out = (float*)d_out;

    unsigned short* ws = (unsigned short*)d_ws;
    unsigned short* Xbf  = ws;                       // 8192*512
    unsigned short* Wqkv = Xbf  + 4194304;           // 1536*512
    unsigned short* Wob  = Wqkv + 786432;            // 512*512
    unsigned short* Qh   = Wob  + 262144;            // [16][4096][64]
    unsigned short* Kh   = Qh   + 4194304;           // [16][4096][64]
    unsigned short* Vt   = Kh   + 4194304;           // [16][64][4096]
    unsigned short* Obf  = Vt   + 4194304;           // [8192][512]

    cast_kernel<<<5120, 256, 0, stream>>>(x, wq, wk, wv, wo, Xbf);

    dim3 g1(64, 12);
    gemm_bt<0><<<g1, 256, 0, stream>>>(Xbf, Wqkv, bv, Qh, Kh, Vt, nullptr);

    dim3 g2(16, 32);
    attn_kernel<<<g2, 256, 0, stream>>>(Qh, Kh, Vt, Obf);

    dim3 g3(64, 4);
    gemm_bt<1><<<g3, 256, 0, stream>>>(Obf, Wob, bo, nullptr, nullptr, nullptr, out);
}

// Round 5
// 119.792 us; speedup vs baseline: 3.8629x; 1.1143x over previous
//
#include <hip/hip_runtime.h>
#include <hip/hip_bf16.h>

#define NB 2
#define SEQ 4096
#define DM 512
#define NH 8
#define DKH 64
#define MTOT (NB*SEQ)   // 8192

typedef __attribute__((ext_vector_type(4))) float f32x4;
typedef __attribute__((ext_vector_type(16))) float f32x16;
typedef __attribute__((ext_vector_type(8))) short bf16x8;
typedef __attribute__((ext_vector_type(2))) unsigned uint2v;

__device__ inline unsigned short f2bf(float f) {
    union { float f; unsigned int u; } v; v.f = f;
    unsigned int r = v.u + 0x7FFFu + ((v.u >> 16) & 1u);
    return (unsigned short)(r >> 16);
}

// Q prescale: 1/sqrt(d_k) * log2(e) so softmax runs in exp2 domain
#define QSCALE 0.18033688011112042f

// ---------------- cast fp32 -> bf16 for x, Wq, Wk, Wv, Wo ----------------
__global__ void cast_kernel(const float* __restrict__ x, const float* __restrict__ wq,
                            const float* __restrict__ wk, const float* __restrict__ wv,
                            const float* __restrict__ wo, unsigned short* __restrict__ dst) {
    const int NX = MTOT*DM;      // 4194304
    const int NW = DM*DM;        // 262144
    int i4 = blockIdx.x * blockDim.x + threadIdx.x;
    long e = (long)i4 * 4;
    if (e >= NX + 4L*NW) return;
    const float* src; long off;
    if (e < NX)           { src = x;  off = e; }
    else if (e < NX+NW)   { src = wq; off = e - NX; }
    else if (e < NX+2*NW) { src = wk; off = e - NX - NW; }
    else if (e < NX+3*NW) { src = wv; off = e - NX - 2*NW; }
    else                  { src = wo; off = e - NX - 3*NW; }
    float4 v = *reinterpret_cast<const float4*>(src + off);
    ushort4 o;
    o.x = f2bf(v.x); o.y = f2bf(v.y); o.z = f2bf(v.z); o.w = f2bf(v.w);
    *reinterpret_cast<ushort4*>(dst + e) = o;
}

// ---------------- B^T GEMM: C[M][N] = A[M][K] * B[N][K]^T ----------------
template<int MODE>
__global__ __launch_bounds__(256, 2) void gemm_bt(
    const unsigned short* __restrict__ A,
    const unsigned short* __restrict__ B,
    const float* __restrict__ bias,      // MODE0: b_v, MODE1: b_o
    unsigned short* __restrict__ Qh, unsigned short* __restrict__ Kh,
    unsigned short* __restrict__ Vt,
    float* __restrict__ Cout)
{
    const int K = 512;
    __shared__ __align__(16) unsigned short As[128*64];
    __shared__ __align__(16) unsigned short Bs[128*64];
    int tid = threadIdx.x;
    int wid = tid >> 6, lane = tid & 63;
    int wr = wid >> 1, wc = wid & 1;
    int brow = blockIdx.x * 128;
    int bcol = blockIdx.y * 128;
    int l15 = lane & 15, l4 = lane >> 4;

    f32x4 acc[4][4] = {};

    for (int kt = 0; kt < K/64; ++kt) {
        __syncthreads();
        // global -> LDS direct (linear dest, inverse-swizzled per-lane source)
        #pragma unroll
        for (int i = 0; i < 4; ++i) {
            int rbase = i*32 + wid*8;
            int row = rbase + (lane >> 3);
            int csrc = (lane & 7) ^ (row & 7);
            const unsigned short* asrc = A + (long)(brow+row)*K + kt*64 + csrc*8;
            __builtin_amdgcn_global_load_lds(
                (const __attribute__((address_space(1))) unsigned int*)asrc,
                (__attribute__((address_space(3))) unsigned int*)&As[rbase*64], 16, 0, 0);
            const unsigned short* bsrc = B + (long)(bcol+row)*K + kt*64 + csrc*8;
            __builtin_amdgcn_global_load_lds(
                (const __attribute__((address_space(1))) unsigned int*)bsrc,
                (__attribute__((address_space(3))) unsigned int*)&Bs[rbase*64], 16, 0, 0);
        }
        __syncthreads();
        #pragma unroll
        for (int kk = 0; kk < 2; ++kk) {
            bf16x8 af[4], bfr[4];
            #pragma unroll
            for (int mi = 0; mi < 4; ++mi) {
                int row = wr*64 + mi*16 + l15;
                int colb = (kk*32 + l4*8) * 2;
                af[mi] = *reinterpret_cast<const bf16x8*>(
                    reinterpret_cast<const char*>(As) + row*128 + (colb ^ ((row&7)<<4)));
            }
            #pragma unroll
            for (int ni = 0; ni < 4; ++ni) {
                int row = wc*64 + ni*16 + l15;
                int colb = (kk*32 + l4*8) * 2;
                bfr[ni] = *reinterpret_cast<const bf16x8*>(
                    reinterpret_cast<const char*>(Bs) + row*128 + (colb ^ ((row&7)<<4)));
            }
            #pragma unroll
            for (int mi = 0; mi < 4; ++mi)
                #pragma unroll
                for (int ni = 0; ni < 4; ++ni)
                    acc[mi][ni] = __builtin_amdgcn_mfma_f32_16x16x32_bf16(af[mi], bfr[ni], acc[mi][ni], 0, 0, 0);
        }
    }

    #pragma unroll
    for (int mi = 0; mi < 4; ++mi) {
        #pragma unroll
        for (int ni = 0; ni < 4; ++ni) {
            #pragma unroll
            for (int r = 0; r < 4; ++r) {
                int row = brow + wr*64 + mi*16 + l4*4 + r;
                int col = bcol + wc*64 + ni*16 + l15;
                float v = acc[mi][ni][r];
                if (MODE == 0) {
                    int which = col >> 9;
                    int cw = col & 511;
                    int h = cw >> 6, d = cw & 63;
                    int b = row >> 12, s = row & 4095;
                    int bh = b*NH + h;
                    if (which == 0) {
                        Qh[((long)(bh*SEQ + s))*DKH + d] = f2bf(v * QSCALE);
                    } else if (which == 1) {
                        Kh[((long)(bh*SEQ + s))*DKH + d] = f2bf(v);
                    } else {
                        Vt[((long)(bh*DKH + d))*SEQ + s] = f2bf(v + bias[cw]);
                    }
                } else {
                    Cout[(long)row*DM + col] = v + bias[col];
                }
            }
        }
    }
}

// ---------------- causal flash attention: 32x32 swapped, KVBLK=128 ----------
// grid (16 bh, 32 ty); block 256 = 4 waves; wave owns 32 q-rows (tile = 128).
// Per iteration: 128 keys = 4 QK chains + 8 PV steps (2x MFMA ILP, half the
// barriers/softmax passes of KVBLK=64).
__global__ __launch_bounds__(256, 2) void attn_kernel(
    const unsigned short* __restrict__ Qh,
    const unsigned short* __restrict__ Kh,
    const unsigned short* __restrict__ Vt,
    unsigned short* __restrict__ Obf)
{
    __shared__ __align__(16) unsigned short Klds[2][128*64];   // [key][d] 128B rows
    __shared__ __align__(16) unsigned short Vlds[2][2*64*64];  // two [d][64key] sub-tiles
    const int tid = threadIdx.x;
    const int wid = tid >> 6, lane = tid & 63;
    const int l31 = lane & 31;
    const int hi  = lane >> 5;
    const int bh  = blockIdx.x;
    const int ty  = blockIdx.y;
    const int tile = ty < 16 ? 31 - ty : ty - 16;   // dispatch-order pairing

    const unsigned short* Qbase = Qh + (long)bh*SEQ*DKH;
    const unsigned short* Kbase = Kh + (long)bh*SEQ*DKH;
    const unsigned short* Vbase = Vt + (long)bh*DKH*SEQ;

    const int q0w = tile*128 + wid*32;
    const int q   = q0w + l31;
    const int nt  = tile + 1;          // 128-key blocks
    const int swz = (l31 & 7) << 4;

    // Q as B-operand frags: qf[kk][e] = Q[q][kk*16 + hi*8 + e]
    bf16x8 qf[4];
    #pragma unroll
    for (int kk = 0; kk < 4; ++kk)
        qf[kk] = *reinterpret_cast<const bf16x8*>(Qbase + (long)q*DKH + kk*16 + hi*8);

    auto STAGE = [&](int b, int key0) {
        // K: 128 rows x 128B, wave stages rows wid*32..+31
        #pragma unroll
        for (int ii = 0; ii < 4; ++ii) {
            const int rbase = wid*32 + ii*8;
            const int row = rbase + (lane >> 3);
            const int ck = (lane & 7) ^ (row & 7);
            const unsigned short* ksrc = Kbase + (long)(key0 + row)*DKH + ck*8;
            __builtin_amdgcn_global_load_lds(
                (const __attribute__((address_space(1))) unsigned int*)ksrc,
                (__attribute__((address_space(3))) unsigned int*)&Klds[b][rbase*64], 16, 0, 0);
        }
        // V: two sub-tiles [64 d][64 keys]; wave stages d-rows wid*16..+15 of each
        #pragma unroll
        for (int jj = 0; jj < 2; ++jj) {
            #pragma unroll
            for (int ii = 0; ii < 2; ++ii) {
                const int rbase = wid*16 + ii*8;
                const int row = rbase + (lane >> 3);
                const int ck = (lane & 7) ^ (row & 7);
                const unsigned short* vsrc = Vbase + (long)row*SEQ + key0 + jj*64 + ck*8;
                __builtin_amdgcn_global_load_lds(
                    (const __attribute__((address_space(1))) unsigned int*)vsrc,
                    (__attribute__((address_space(3))) unsigned int*)&Vlds[b][jj*4096 + rbase*64], 16, 0, 0);
            }
        }
    };

    float m = -1e30f, lsum = 0.f;
    f32x16 od0 = {}, od1 = {};

    STAGE(0, 0);
    __syncthreads();
    int cur = 0;

    for (int kb = 0; kb < nt; ++kb) {
        if (kb + 1 < nt) STAGE(cur ^ 1, (kb + 1) << 7);
        const char* kl = reinterpret_cast<const char*>(Klds[cur]);
        const char* vl = reinterpret_cast<const char*>(Vlds[cur]);
        const int key0 = kb << 7;

        // QK^T (swapped): 4 independent chains, keys key0 + 32*c
        f32x16 s0 = {}, s1 = {}, s2 = {}, s3 = {};
        __builtin_amdgcn_s_setprio(1);
        #pragma unroll
        for (int kk = 0; kk < 4; ++kk) {
            const int co = (kk*32 + hi*16) ^ swz;
            bf16x8 kf0 = *reinterpret_cast<const bf16x8*>(kl + l31*128       + co);
            s0 = __builtin_amdgcn_mfma_f32_32x32x16_bf16(kf0, qf[kk], s0, 0, 0, 0);
            bf16x8 kf1 = *reinterpret_cast<const bf16x8*>(kl + (32+l31)*128  + co);
            s1 = __builtin_amdgcn_mfma_f32_32x32x16_bf16(kf1, qf[kk], s1, 0, 0, 0);
            bf16x8 kf2 = *reinterpret_cast<const bf16x8*>(kl + (64+l31)*128  + co);
            s2 = __builtin_amdgcn_mfma_f32_32x32x16_bf16(kf2, qf[kk], s2, 0, 0, 0);
            bf16x8 kf3 = *reinterpret_cast<const bf16x8*>(kl + (96+l31)*128  + co);
            s3 = __builtin_amdgcn_mfma_f32_32x32x16_bf16(kf3, qf[kk], s3, 0, 0, 0);
        }
        __builtin_amdgcn_s_setprio(0);

        // causal mask (diagonal block only): key of reg r = key0 + 32c + (r&3)+8*(r>>2)+4*hi
        if (key0 + 127 > q0w) {
            #pragma unroll
            for (int r = 0; r < 16; ++r) {
                const int ko = (r&3) + 8*(r>>2) + 4*hi;
                if (key0 + ko > q)      s0[r] = -1e30f;
                if (key0 + 32 + ko > q) s1[r] = -1e30f;
                if (key0 + 64 + ko > q) s2[r] = -1e30f;
                if (key0 + 96 + ko > q) s3[r] = -1e30f;
            }
        }

        // row max: in-lane tree over 64 + partner exchange
        float pmax = s0[0];
        #pragma unroll
        for (int r = 1; r < 16; ++r) pmax = fmaxf(pmax, s0[r]);
        #pragma unroll
        for (int r = 0; r < 16; ++r) pmax = fmaxf(pmax, fmaxf(s1[r], fmaxf(s2[r], s3[r])));
        {
            uint2v pr = __builtin_amdgcn_permlane32_swap(__float_as_uint(pmax), __float_as_uint(pmax), false, false);
            pmax = fmaxf(__uint_as_float(pr[0]), __uint_as_float(pr[1]));
        }

        // defer-max (T13): rescale only when max grows past threshold
        if (__any(pmax > m + 6.0f)) {
            const float mn = fmaxf(m, pmax);
            const float alpha = __builtin_amdgcn_exp2f(m - mn);
            m = mn;
            lsum *= alpha;
            #pragma unroll
            for (int r = 0; r < 16; ++r) { od0[r] *= alpha; od1[r] *= alpha; }
        }

        // P = exp2(S - m) in place; per-lane lsum partial
        float rs = 0.f;
        #pragma unroll
        for (int r = 0; r < 16; ++r) {
            s0[r] = __builtin_amdgcn_exp2f(s0[r] - m);
            s1[r] = __builtin_amdgcn_exp2f(s1[r] - m);
            s2[r] = __builtin_amdgcn_exp2f(s2[r] - m);
            s3[r] = __builtin_amdgcn_exp2f(s3[r] - m);
            rs += (s0[r] + s1[r]) + (s2[r] + s3[r]);
        }
        lsum += rs;

        // P -> bf16 B-frags in-register (cvt_pk + permlane32_swap), then PV
        __builtin_amdgcn_s_setprio(1);
#define PV_STEP(SV, VLS, KS, B0) do {                                              \
        unsigned c0, c1, c2, c3;                                                   \
        float t0 = SV[B0+0], t1 = SV[B0+1], t2 = SV[B0+2], t3 = SV[B0+3];          \
        float t4 = SV[B0+4], t5 = SV[B0+5], t6 = SV[B0+6], t7 = SV[B0+7];          \
        asm("v_cvt_pk_bf16_f32 %0, %1, %2" : "=v"(c0) : "v"(t0), "v"(t1));         \
        asm("v_cvt_pk_bf16_f32 %0, %1, %2" : "=v"(c1) : "v"(t2), "v"(t3));         \
        asm("v_cvt_pk_bf16_f32 %0, %1, %2" : "=v"(c2) : "v"(t4), "v"(t5));         \
        asm("v_cvt_pk_bf16_f32 %0, %1, %2" : "=v"(c3) : "v"(t6), "v"(t7));         \
        uint2v sw0 = __builtin_amdgcn_permlane32_swap(c0, c2, false, false);       \
        uint2v sw1 = __builtin_amdgcn_permlane32_swap(c1, c3, false, false);       \
        union { unsigned u[4]; bf16x8 v; } pu;                                     \
        pu.u[0] = sw0[0]; pu.u[1] = sw1[0]; pu.u[2] = sw0[1]; pu.u[3] = sw1[1];    \
        bf16x8 vf0 = *reinterpret_cast<const bf16x8*>(VLS + l31*128      + (((KS)*32 + hi*16) ^ swz)); \
        od0 = __builtin_amdgcn_mfma_f32_32x32x16_bf16(vf0, pu.v, od0, 0, 0, 0);    \
        bf16x8 vf1 = *reinterpret_cast<const bf16x8*>(VLS + (32+l31)*128 + (((KS)*32 + hi*16) ^ swz)); \
        od1 = __builtin_amdgcn_mfma_f32_32x32x16_bf16(vf1, pu.v, od1, 0, 0, 0);    \
    } while (0)
        const char* vl0 = vl;          // keys key0 + 0..63
        const char* vl1 = vl + 8192;   // keys key0 + 64..127
        PV_STEP(s0, vl0, 0, 0);
        PV_STEP(s0, vl0, 1, 8);
        PV_STEP(s1, vl0, 2, 0);
        PV_STEP(s1, vl0, 3, 8);
        PV_STEP(s2, vl1, 0, 0);
        PV_STEP(s2, vl1, 1, 8);
        PV_STEP(s3, vl1, 2, 0);
        PV_STEP(s3, vl1, 3, 8);
#undef PV_STEP
        __builtin_amdgcn_s_setprio(0);

        __syncthreads();
        cur ^= 1;
    }

    // combine partner lsum, normalize, write O
    {
        uint2v pr = __builtin_amdgcn_permlane32_swap(__float_as_uint(lsum), __float_as_uint(lsum), false, false);
        lsum = __uint_as_float(pr[0]) + __uint_as_float(pr[1]);
    }
    const float rls = 1.0f / lsum;
    const long obase = (long)((bh >> 3)*SEQ + q)*DM + (bh & 7)*DKH;
    #pragma unroll
    for (int rr = 0; rr < 4; ++rr) {
        ushort4 w0, w1;
        w0.x = f2bf(od0[rr*4+0]*rls); w0.y = f2bf(od0[rr*4+1]*rls);
        w0.z = f2bf(od0[rr*4+2]*rls); w0.w = f2bf(od0[rr*4+3]*rls);
        *reinterpret_cast<ushort4*>(Obf + obase + rr*8 + hi*4) = w0;
        w1.x = f2bf(od1[rr*4+0]*rls); w1.y = f2bf(od1[rr*4+1]*rls);
        w1.z = f2bf(od1[rr*4+2]*rls); w1.w = f2bf(od1[rr*4+3]*rls);
        *reinterpret_cast<ushort4*>(Obf + obase + 32 + rr*8 + hi*4) = w1;
    }
}

extern "C" void kernel_launch(void* const* d_in, const int* in_sizes, int n_in,
                              void* d_out, int out_size, void* d_ws, size_t ws_size,
                              hipStream_t stream) {
    const float* x  = (const float*)d_in[0];
    const float* wq = (const float*)d_in[1];
    const float* wk = (const float*)d_in[2];
    const float* wv = (const float*)d_in[3];
    const float* bv = (const float*)d_in[4];
    const float* wo = (const float*)d_in[5];
    const float* bo = (const float*)d_in[6];
    float* out = (float*)d_out;

    unsigned short* ws = (unsigned short*)d_ws;
    unsigned short* Xbf  = ws;                       // 8192*512
    unsigned short* Wqkv = Xbf  + 4194304;           // 1536*512
    unsigned short* Wob  = Wqkv + 786432;            // 512*512
    unsigned short* Qh   = Wob  + 262144;            // [16][4096][64]
    unsigned short* Kh   = Qh   + 4194304;           // [16][4096][64]
    unsigned short* Vt   = Kh   + 4194304;           // [16][64][4096]
    unsigned short* Obf  = Vt   + 4194304;           // [8192][512]

    cast_kernel<<<5120, 256, 0, stream>>>(x, wq, wk, wv, wo, Xbf);

    dim3 g1(64, 12);
    gemm_bt<0><<<g1, 256, 0, stream>>>(Xbf, Wqkv, bv, Qh, Kh, Vt, nullptr);

    dim3 g2(16, 32);
    attn_kernel<<<g2, 256, 0, stream>>>(Qh, Kh, Vt, Obf);

    dim3 g3(64, 4);
    gemm_bt<1><<<g3, 256, 0, stream>>>(Obf, Wob, bo, nullptr, nullptr, nullptr, out);
}